// Round 5
// baseline (389.814 us; speedup 1.0000x reference)
//
#include <hip/hip_runtime.h>
#include <hip/hip_bf16.h>

typedef __attribute__((ext_vector_type(8))) short short8;
typedef __attribute__((ext_vector_type(4))) float f32x4;

#define BN_EPS 1e-5f
#define MROWS 4096
#define CDIM 2048

#define SB() __builtin_amdgcn_sched_barrier(0)

__device__ __forceinline__ void gload_lds16(const void* g, void* l) {
  __builtin_amdgcn_global_load_lds(
      (const __attribute__((address_space(1))) void*)g,
      (__attribute__((address_space(3))) void*)l, 16, 0, 0);
}

// ---------------------------------------------------------------------------
// fp32 -> bf16 conversion (vectorized float4 -> ushort4)
// ---------------------------------------------------------------------------
__global__ __launch_bounds__(256) void cvt_f32_bf16(const float* __restrict__ in,
                                                    unsigned short* __restrict__ out,
                                                    int n4) {
  int idx = blockIdx.x * blockDim.x + threadIdx.x;
  int stride = gridDim.x * blockDim.x;
  for (int i = idx; i < n4; i += stride) {
    float4 vv = ((const float4*)in)[i];
    __hip_bfloat16 h0 = __float2bfloat16(vv.x);
    __hip_bfloat16 h1 = __float2bfloat16(vv.y);
    __hip_bfloat16 h2 = __float2bfloat16(vv.z);
    __hip_bfloat16 h3 = __float2bfloat16(vv.w);
    ushort4 o;
    o.x = *(unsigned short*)&h0;
    o.y = *(unsigned short*)&h1;
    o.z = *(unsigned short*)&h2;
    o.w = *(unsigned short*)&h3;
    ((ushort4*)out)[i] = o;
  }
}

// ---------------------------------------------------------------------------
// 128x256 tile, BK=32, 3-deep LDS ring, 2 blocks/CU (4 waves/SIMD TLP).
// 8 waves (2M x 4N) of 64x64, acc[4][4] (64 AGPR); VGPR+AGPR <= 128.
// Grid 768 = 256 tiles/head x 3 heads -> exactly 3 blocks per CU, no tail.
// Swizzle: chunk' = chunk ^ ((row>>1)&3) (conflict-free b128 reads, 64B rows),
// applied involutively on the global staging source (linear LDS dest).
// out[h][m][d] = relu((sum_c A[h][m][c]*W[h][d][c])*scale + shift)
// ---------------------------------------------------------------------------
__global__ __launch_bounds__(512, 4) void gemm128_bn_relu(
    const __hip_bfloat16* __restrict__ A, long long a_hstride,
    const __hip_bfloat16* __restrict__ W,
    const float* __restrict__ gp, const float* __restrict__ bp,
    const float* __restrict__ mp, const float* __restrict__ vp,
    __hip_bfloat16* __restrict__ out)
{
  __shared__ __hip_bfloat16 sm[36864];   // 72 KiB = 3 bufs x 12288 elems

  const int tid  = threadIdx.x;
  const int w    = tid >> 6;
  const int lane = tid & 63;

  // XCD-bijective swizzle over 768 blocks (768 % 8 == 0, q = 96)
  const int bid = blockIdx.x;
  const int swz = (bid & 7) * 96 + (bid >> 3);
  const int h   = swz >> 8;          // 256 tiles per head
  const int rem = swz & 255;
  const int mt  = rem >> 3;          // 32 m-tiles of 128
  const int nt  = rem & 7;           // 8 n-tiles of 256

  const __hip_bfloat16* Abase = A + (size_t)h * (size_t)a_hstride + (size_t)(mt * 128) * CDIM;
  const __hip_bfloat16* Bbase = W + ((size_t)h * CDIM + (size_t)(nt * 256)) * CDIM;

  // staging: A tile 128x32 = 512 slots(16B), B tile 256x32 = 1024 slots.
  // thread -> A slot tid, B slots tid and tid+512. row = slot>>2, chunk = slot&3.
  // global chunk fetched = chunk ^ ((row>>1)&3)  (involution; rowB1 adds 128 -> same adj)
  const int rowA = tid >> 2;
  const int chA  = (tid & 3) ^ ((rowA >> 1) & 3);
  const __hip_bfloat16* aSrc  = Abase + (size_t)rowA * CDIM + chA * 8;
  const __hip_bfloat16* bSrc0 = Bbase + (size_t)rowA * CDIM + chA * 8;
  const __hip_bfloat16* bSrc1 = bSrc0 + (size_t)128 * CDIM;

  // fragment read offsets (swizzled)
  const int wm = w >> 2, wn = w & 3;
  const int fr = lane & 15, fg = lane >> 4;
  const int cadj  = (fg ^ ((fr >> 1) & 3)) * 8;
  const int abase = (wm * 64 + fr) * 32 + cadj;          // A region: elems 0..4095
  const int bbase = 4096 + (wn * 64 + fr) * 32 + cadj;   // B region: elems 4096..12287

  auto STAGE = [&](int off, int t) {
    __hip_bfloat16* dp = &sm[off + tid * 8];
    gload_lds16(aSrc  + t * 32, dp);
    gload_lds16(bSrc0 + t * 32, dp + 4096);
    gload_lds16(bSrc1 + t * 32, dp + 8192);
  };

  f32x4 acc[4][4] = {};

  // prologue: stage tiles 0,1 into bufs 0,1; wait buf0 (3 newest may fly)
  STAGE(0, 0);
  STAGE(12288, 1);
  asm volatile("s_waitcnt vmcnt(3)" ::: "memory");
  SB();
  __builtin_amdgcn_s_barrier();
  SB();

  int oc = 0, on = 12288, os = 24576;
  for (int t = 0; t < 64; ++t) {
    if (t + 2 < 64) STAGE(os, t + 2);
    SB();
    short8 af[4], bf_[4];
#pragma unroll
    for (int i = 0; i < 4; ++i) af[i]  = *(const short8*)&sm[oc + abase + i * 512];
#pragma unroll
    for (int j = 0; j < 4; ++j) bf_[j] = *(const short8*)&sm[oc + bbase + j * 512];
    __builtin_amdgcn_s_setprio(1);
#pragma unroll
    for (int i = 0; i < 4; ++i)
#pragma unroll
      for (int j = 0; j < 4; ++j)
        acc[i][j] = __builtin_amdgcn_mfma_f32_16x16x32_bf16(af[i], bf_[j], acc[i][j], 0, 0, 0);
    __builtin_amdgcn_s_setprio(0);
    SB();
    if (t < 63) {
      if (t + 2 < 64) { asm volatile("s_waitcnt vmcnt(3)" ::: "memory"); }
      else            { asm volatile("s_waitcnt vmcnt(0)" ::: "memory"); }
      SB();
      __builtin_amdgcn_s_barrier();
      SB();
    }
    const int tmp = oc; oc = on; on = os; os = tmp;
  }

  // epilogue: BN (folded) + ReLU, bf16 store.
  // C/D layout: col = lane&15, row = (lane>>4)*4 + reg  [m89 verified]
  const float* gh = gp + h * CDIM;
  const float* bh = bp + h * CDIM;
  const float* mh = mp + h * CDIM;
  const float* vh = vp + h * CDIM;
  const int colBase = nt * 256 + wn * 64 + fr;
  const int rowBase = mt * 128 + wm * 64 + fg * 4;
#pragma unroll
  for (int j = 0; j < 4; ++j) {
    const int col = colBase + j * 16;
    const float sc = gh[col] / sqrtf(vh[col] + BN_EPS);
    const float sh = bh[col] - mh[col] * sc;
#pragma unroll
    for (int i = 0; i < 4; ++i) {
      const int row = rowBase + i * 16;
#pragma unroll
      for (int rr = 0; rr < 4; ++rr) {
        float val = acc[i][j][rr] * sc + sh;
        val = val > 0.f ? val : 0.f;
        out[((size_t)h * MROWS + row + rr) * CDIM + col] = __float2bfloat16(val);
      }
    }
  }
}

// ---------------------------------------------------------------------------
// Pack final-layer weights into bf16 Wfb[3][16][2048], zero-padded.
// ---------------------------------------------------------------------------
__global__ __launch_bounds__(256) void pack_wf(
    const float* __restrict__ Wf0, const float* __restrict__ Wf1,
    const float* __restrict__ Wf2, __hip_bfloat16* __restrict__ Wfb) {
  int idx = blockIdx.x * 256 + threadIdx.x;   // 3*16*2048 = 98304
  if (idx >= 3 * 16 * CDIM) return;
  int h = idx / (16 * CDIM);
  int rem = idx - h * 16 * CDIM;
  int j = rem / CDIM;
  int k = rem - j * CDIM;
  float v = 0.f;
  if (h == 0)            v = Wf0[j * CDIM + k];
  else if (h == 1)       { if (j < 5) v = Wf1[j * CDIM + k]; }
  else                   { if (j < 5) v = Wf2[j * CDIM + k]; }
  Wfb[idx] = __float2bfloat16(v);
}

// ---------------------------------------------------------------------------
// Final 1x1 convs via MFMA, K-split 8 ways across waves.
// ---------------------------------------------------------------------------
__global__ __launch_bounds__(512) void final_mfma(
    const __hip_bfloat16* __restrict__ act,   // [3][4096][2048]
    const __hip_bfloat16* __restrict__ Wfb,   // [3][16][2048]
    const float* __restrict__ bf0, const float* __restrict__ bf1,
    const float* __restrict__ bf2, float* __restrict__ out)  // [4096][26]
{
  __shared__ float red[8][3][256];
  const int tid  = threadIdx.x;
  const int w    = tid >> 6;
  const int lane = tid & 63;
  const int r0   = blockIdx.x * 16;
  const int fr   = lane & 15;
  const int fk   = (lane >> 4) * 8;
  const int kbase = w * 256 + fk;

  f32x4 acc[3] = {};
  const __hip_bfloat16* aRow = act + (size_t)(r0 + fr) * CDIM + kbase;
  const __hip_bfloat16* bRow = Wfb + (size_t)fr * CDIM + kbase;
#pragma unroll
  for (int ks = 0; ks < 8; ++ks) {
    const int k = ks * 32;
#pragma unroll
    for (int h = 0; h < 3; ++h) {
      short8 a = *(const short8*)(aRow + (size_t)h * MROWS * CDIM + k);
      short8 b = *(const short8*)(bRow + h * 16 * CDIM + k);
      acc[h] = __builtin_amdgcn_mfma_f32_16x16x32_bf16(a, b, acc[h], 0, 0, 0);
    }
  }

  const int rb = (lane >> 4) * 4;
#pragma unroll
  for (int h = 0; h < 3; ++h)
#pragma unroll
    for (int r = 0; r < 4; ++r)
      red[w][h][(rb + r) * 16 + fr] = acc[h][r];
  __syncthreads();

  for (int e = tid; e < 768; e += 512) {
    const int h = e >> 8, idx = e & 255;
    const int row = idx >> 4, col = idx & 15;
    float s = 0.f;
#pragma unroll
    for (int w2 = 0; w2 < 8; ++w2) s += red[w2][h][idx];
    float* orow = out + (size_t)(r0 + row) * 26;
    if (h == 0)                 orow[col]      = s + bf0[col];
    else if (h == 1) { if (col < 5) orow[16 + col] = s + bf1[col]; }
    else             { if (col < 5) orow[21 + col] = s + bf2[col]; }
  }
}

// ---------------------------------------------------------------------------
extern "C" void kernel_launch(void* const* d_in, const int* in_sizes, int n_in,
                              void* d_out, int out_size, void* d_ws, size_t ws_size,
                              hipStream_t stream) {
  const float* feat = (const float*)d_in[0];
  const float* W1 = (const float*)d_in[1];
  const float* g1 = (const float*)d_in[2];
  const float* b1 = (const float*)d_in[3];
  const float* m1 = (const float*)d_in[4];
  const float* v1 = (const float*)d_in[5];
  const float* W2 = (const float*)d_in[6];
  const float* g2 = (const float*)d_in[7];
  const float* b2 = (const float*)d_in[8];
  const float* m2 = (const float*)d_in[9];
  const float* v2 = (const float*)d_in[10];
  const float* W3 = (const float*)d_in[11];
  const float* g3 = (const float*)d_in[12];
  const float* b3 = (const float*)d_in[13];
  const float* m3 = (const float*)d_in[14];
  const float* v3 = (const float*)d_in[15];
  const float* Wf0 = (const float*)d_in[16];
  const float* bf0 = (const float*)d_in[17];
  const float* Wf1 = (const float*)d_in[18];
  const float* bf1 = (const float*)d_in[19];
  const float* Wf2 = (const float*)d_in[20];
  const float* bf2 = (const float*)d_in[21];
  float* out = (float*)d_out;

  // workspace: wbuf 24MB | actA 48MB | actB 48MB (features bf16 overlaps actB)
  // Wfb (192KB) reuses wbuf after gemm3 has consumed W3.
  char* ws = (char*)d_ws;
  __hip_bfloat16* wbuf = (__hip_bfloat16*)ws;
  __hip_bfloat16* actA = (__hip_bfloat16*)(ws + 25165824);
  __hip_bfloat16* actB = (__hip_bfloat16*)(ws + 25165824 + 50331648);
  __hip_bfloat16* xb   = actB;
  __hip_bfloat16* Wfb  = wbuf;

  const int nW4 = (3 * CDIM * CDIM) / 4;
  const int nX4 = (MROWS * CDIM) / 4;
  const long long hstride = (long long)MROWS * CDIM;

  cvt_f32_bf16<<<2048, 256, 0, stream>>>(feat, (unsigned short*)xb, nX4);

  cvt_f32_bf16<<<2048, 256, 0, stream>>>(W1, (unsigned short*)wbuf, nW4);
  gemm128_bn_relu<<<768, 512, 0, stream>>>(xb, 0LL, wbuf, g1, b1, m1, v1, actA);

  cvt_f32_bf16<<<2048, 256, 0, stream>>>(W2, (unsigned short*)wbuf, nW4);
  gemm128_bn_relu<<<768, 512, 0, stream>>>(actA, hstride, wbuf, g2, b2, m2, v2, actB);

  cvt_f32_bf16<<<2048, 256, 0, stream>>>(W3, (unsigned short*)wbuf, nW4);
  gemm128_bn_relu<<<768, 512, 0, stream>>>(actB, hstride, wbuf, g3, b3, m3, v3, actA);

  pack_wf<<<384, 256, 0, stream>>>(Wf0, Wf1, Wf2, Wfb);
  final_mfma<<<256, 512, 0, stream>>>(actA, Wfb, bf0, bf1, bf2, out);
}

// Round 6
// 363.425 us; speedup vs baseline: 1.0726x; 1.0726x over previous
//
#include <hip/hip_runtime.h>
#include <hip/hip_bf16.h>

typedef __attribute__((ext_vector_type(8))) short short8;
typedef __attribute__((ext_vector_type(4))) float f32x4;

#define BN_EPS 1e-5f
#define MROWS 4096
#define CDIM 2048
#define NKT 32   // K tiles of 64

#define SB() __builtin_amdgcn_sched_barrier(0)

__device__ __forceinline__ void gload_lds16(const void* g, void* l) {
  __builtin_amdgcn_global_load_lds(
      (const __attribute__((address_space(1))) void*)g,
      (__attribute__((address_space(3))) void*)l, 16, 0, 0);
}

// ---------------------------------------------------------------------------
// fp32 -> bf16 conversion (vectorized float4 -> ushort4)
// ---------------------------------------------------------------------------
__global__ __launch_bounds__(256) void cvt_f32_bf16(const float* __restrict__ in,
                                                    unsigned short* __restrict__ out,
                                                    int n4) {
  int idx = blockIdx.x * blockDim.x + threadIdx.x;
  int stride = gridDim.x * blockDim.x;
  for (int i = idx; i < n4; i += stride) {
    float4 vv = ((const float4*)in)[i];
    __hip_bfloat16 h0 = __float2bfloat16(vv.x);
    __hip_bfloat16 h1 = __float2bfloat16(vv.y);
    __hip_bfloat16 h2 = __float2bfloat16(vv.z);
    __hip_bfloat16 h3 = __float2bfloat16(vv.w);
    ushort4 o;
    o.x = *(unsigned short*)&h0;
    o.y = *(unsigned short*)&h1;
    o.z = *(unsigned short*)&h2;
    o.w = *(unsigned short*)&h3;
    ((ushort4*)out)[i] = o;
  }
}

// ---------------------------------------------------------------------------
// 128x256 tile, BK=64, 3-deep LDS ring (144 KiB -> exactly 1 block/CU).
// Grid 768 = 3 blocks/CU exact => zero quantization tail.
// 8 waves (2M x 4N) of 64x64, acc[4][4] (64 AGPR).
// Fragment-rotated schedule: 4 groups of 8 MFMA per K-tile; trailing
// ds_reads refill >=2 groups ahead; stages for t+2 go to ring slot (t+2)%3
// (never read during tile t => ring gives write-safety, not barriers).
// 1 barrier + 1 counted vmcnt per K-tile.
// Swizzle chunk^=(row&7) on 16B chunks (R3-verified, 0 conflicts).
// out[h][m][d] = relu((sum_c A[h][m][c]*W[h][d][c])*scale + shift)
// ---------------------------------------------------------------------------
__global__ __launch_bounds__(512, 2) void gemm128_ring(
    const __hip_bfloat16* __restrict__ A, long long a_hstride,
    const __hip_bfloat16* __restrict__ W,
    const float* __restrict__ gp, const float* __restrict__ bp,
    const float* __restrict__ mp, const float* __restrict__ vp,
    __hip_bfloat16* __restrict__ out)
{
  __shared__ __hip_bfloat16 sm[73728];   // 144 KiB = 3 x 24576 elems

  const int tid  = threadIdx.x;
  const int w    = tid >> 6;
  const int lane = tid & 63;

  // XCD-bijective swizzle over 768 blocks (768 % 8 == 0, q = 96)
  const int bid = blockIdx.x;
  const int swz = (bid & 7) * 96 + (bid >> 3);
  const int h   = swz >> 8;          // 256 tiles per head
  const int rem = swz & 255;
  const int mt  = rem >> 3;          // 32 m-tiles of 128
  const int nt  = rem & 7;           // 8 n-tiles of 256

  const __hip_bfloat16* Abase = A + (size_t)h * (size_t)a_hstride + (size_t)(mt * 128) * CDIM;
  const __hip_bfloat16* Bbase = W + ((size_t)h * CDIM + (size_t)(nt * 256)) * CDIM;

  // staging: A tile 128x64 = 1024 16B slots (thread t: slots t, t+512);
  // B tile 256x64 = 2048 slots (slots t + 512k, k=0..3).
  // slot s: row = s>>3, chunk = s&7, global chunk = chunk ^ (row&7).
  // rows step by 64 between a thread's slots => same &7 => same chunk adj.
  const int row0 = tid >> 3;
  const int ch0  = (tid & 7) ^ (row0 & 7);
  const __hip_bfloat16* aSrc = Abase + (size_t)row0 * CDIM + ch0 * 8;
  const __hip_bfloat16* bSrc = Bbase + (size_t)row0 * CDIM + ch0 * 8;

  // fragment read offsets (swizzled; row&7 == fr&7 since 16,64 are mult of 8)
  const int wm = w >> 2, wn = w & 3;
  const int fr = lane & 15, fg = lane >> 4;
  const int offs0 = fr * 64 + ((fg ^ (fr & 7)) << 3);        // ksub 0
  const int offs1 = fr * 64 + (((fg + 4) ^ (fr & 7)) << 3);  // ksub 1
  const int aoffs0 = wm * 4096 + offs0;
  const int aoffs1 = wm * 4096 + offs1;
  const int boffs0 = 8192 + wn * 4096 + offs0;
  const int boffs1 = 8192 + wn * 4096 + offs1;

  auto SA = [&](int buf, int t) {
    __hip_bfloat16* dp = &sm[buf + tid * 8];
    gload_lds16(aSrc + t * 64, dp);
    gload_lds16(aSrc + (size_t)64 * CDIM + t * 64, dp + 4096);
  };
  auto SB0 = [&](int buf, int t) {
    __hip_bfloat16* dp = &sm[buf + 8192 + tid * 8];
    gload_lds16(bSrc + t * 64, dp);
    gload_lds16(bSrc + (size_t)64 * CDIM + t * 64, dp + 4096);
  };
  auto SB1 = [&](int buf, int t) {
    __hip_bfloat16* dp = &sm[buf + 8192 + 8192 + tid * 8];
    gload_lds16(bSrc + (size_t)128 * CDIM + t * 64, dp);
    gload_lds16(bSrc + (size_t)192 * CDIM + t * 64, dp + 4096);
  };

  f32x4 acc[4][4] = {};
  short8 Af[4], Ap[4], B0[2], B1[2], B0p[2], B1p[2];

#define LDA4(dst, base)                                                  \
  _Pragma("unroll") for (int i_ = 0; i_ < 4; ++i_)                       \
    dst[i_] = *(const short8*)&sm[(base) + i_ * 1024];
#define LDB2(dst, base, j0)                                              \
  _Pragma("unroll") for (int j_ = 0; j_ < 2; ++j_)                       \
    dst[j_] = *(const short8*)&sm[(base) + ((j0) + j_) * 1024];

#define MFMA_G(joff, Aset, Bset)                                         \
  __builtin_amdgcn_s_setprio(1);                                         \
  _Pragma("unroll") for (int i_ = 0; i_ < 4; ++i_)                       \
  _Pragma("unroll") for (int j_ = 0; j_ < 2; ++j_)                       \
    acc[i_][j_ + joff] = __builtin_amdgcn_mfma_f32_16x16x32_bf16(        \
        Aset[i_], Bset[j_], acc[i_][j_ + joff], 0, 0, 0);                \
  __builtin_amdgcn_s_setprio(0);

  // ---- prologue: stage tiles 0,1 into ring slots 0,1; read t0 ks0 frags ----
  SA(0, 0); SB0(0, 0); SB1(0, 0);
  SA(24576, 1); SB0(24576, 1); SB1(24576, 1);
  asm volatile("s_waitcnt vmcnt(6)" ::: "memory");
  SB();
  __builtin_amdgcn_s_barrier();
  SB();
  LDA4(Af, 0 + aoffs0);
  LDB2(B0, 0 + boffs0, 0);
  LDB2(B1, 0 + boffs0, 2);
  SB();

  int oc = 0, on = 24576, os = 49152;
  for (int t = 0; t < NKT; ++t) {
    // g0: ks0 j01; refill B0p <- ks1
    MFMA_G(0, Af, B0); SB();
    LDB2(B0p, oc + boffs1, 0); SB();
    // g1: ks0 j23; refill Ap <- ks1; stage A(t+2)
    MFMA_G(2, Af, B1); SB();
    LDA4(Ap, oc + aoffs1);
    if (t + 2 < NKT) SA(os, t + 2);
    SB();
    // g2: ks1 j01; refill B1p <- ks1; stage B0(t+2)
    MFMA_G(0, Ap, B0p); SB();
    LDB2(B1p, oc + boffs1, 2);
    if (t + 2 < NKT) SB0(os, t + 2);
    SB();
    // g3: ks1 j23; stage B1(t+2)
    MFMA_G(2, Ap, B1p); SB();
    if (t + 2 < NKT) SB1(os, t + 2);
    SB();
    if (t < NKT - 1) {
      if (t + 2 < NKT) { asm volatile("s_waitcnt vmcnt(6)" ::: "memory"); }
      else             { asm volatile("s_waitcnt vmcnt(0)" ::: "memory"); }
      SB();
      __builtin_amdgcn_s_barrier();
      SB();
      LDA4(Af, on + aoffs0);
      LDB2(B0, on + boffs0, 0);
      LDB2(B1, on + boffs0, 2);
      SB();
    }
    const int tmp = oc; oc = on; on = os; os = tmp;
  }

  // epilogue: BN (folded) + ReLU, bf16 store.
  // C/D layout: col = lane&15, row = (lane>>4)*4 + reg  [m89 verified]
  const float* gh = gp + h * CDIM;
  const float* bh = bp + h * CDIM;
  const float* mh = mp + h * CDIM;
  const float* vh = vp + h * CDIM;
  const int colBase = nt * 256 + wn * 64 + fr;
  const int rowBase = mt * 128 + wm * 64 + fg * 4;
#pragma unroll
  for (int j = 0; j < 4; ++j) {
    const int col = colBase + j * 16;
    const float sc = gh[col] / sqrtf(vh[col] + BN_EPS);
    const float sh = bh[col] - mh[col] * sc;
#pragma unroll
    for (int i = 0; i < 4; ++i) {
      const int row = rowBase + i * 16;
#pragma unroll
      for (int rr = 0; rr < 4; ++rr) {
        float val = acc[i][j][rr] * sc + sh;
        val = val > 0.f ? val : 0.f;
        out[((size_t)h * MROWS + row + rr) * CDIM + col] = __float2bfloat16(val);
      }
    }
  }
}

// ---------------------------------------------------------------------------
// Pack final-layer weights into bf16 Wfb[3][16][2048], zero-padded.
// ---------------------------------------------------------------------------
__global__ __launch_bounds__(256) void pack_wf(
    const float* __restrict__ Wf0, const float* __restrict__ Wf1,
    const float* __restrict__ Wf2, __hip_bfloat16* __restrict__ Wfb) {
  int idx = blockIdx.x * 256 + threadIdx.x;   // 3*16*2048 = 98304
  if (idx >= 3 * 16 * CDIM) return;
  int h = idx / (16 * CDIM);
  int rem = idx - h * 16 * CDIM;
  int j = rem / CDIM;
  int k = rem - j * CDIM;
  float v = 0.f;
  if (h == 0)            v = Wf0[j * CDIM + k];
  else if (h == 1)       { if (j < 5) v = Wf1[j * CDIM + k]; }
  else                   { if (j < 5) v = Wf2[j * CDIM + k]; }
  Wfb[idx] = __float2bfloat16(v);
}

// ---------------------------------------------------------------------------
// Final 1x1 convs via MFMA, K-split 8 ways across waves.
// ---------------------------------------------------------------------------
__global__ __launch_bounds__(512) void final_mfma(
    const __hip_bfloat16* __restrict__ act,   // [3][4096][2048]
    const __hip_bfloat16* __restrict__ Wfb,   // [3][16][2048]
    const float* __restrict__ bf0, const float* __restrict__ bf1,
    const float* __restrict__ bf2, float* __restrict__ out)  // [4096][26]
{
  __shared__ float red[8][3][256];
  const int tid  = threadIdx.x;
  const int w    = tid >> 6;
  const int lane = tid & 63;
  const int r0   = blockIdx.x * 16;
  const int fr   = lane & 15;
  const int fk   = (lane >> 4) * 8;
  const int kbase = w * 256 + fk;

  f32x4 acc[3] = {};
  const __hip_bfloat16* aRow = act + (size_t)(r0 + fr) * CDIM + kbase;
  const __hip_bfloat16* bRow = Wfb + (size_t)fr * CDIM + kbase;
#pragma unroll
  for (int ks = 0; ks < 8; ++ks) {
    const int k = ks * 32;
#pragma unroll
    for (int h = 0; h < 3; ++h) {
      short8 a = *(const short8*)(aRow + (size_t)h * MROWS * CDIM + k);
      short8 b = *(const short8*)(bRow + h * 16 * CDIM + k);
      acc[h] = __builtin_amdgcn_mfma_f32_16x16x32_bf16(a, b, acc[h], 0, 0, 0);
    }
  }

  const int rb = (lane >> 4) * 4;
#pragma unroll
  for (int h = 0; h < 3; ++h)
#pragma unroll
    for (int r = 0; r < 4; ++r)
      red[w][h][(rb + r) * 16 + fr] = acc[h][r];
  __syncthreads();

  for (int e = tid; e < 768; e += 512) {
    const int h = e >> 8, idx = e & 255;
    const int row = idx >> 4, col = idx & 15;
    float s = 0.f;
#pragma unroll
    for (int w2 = 0; w2 < 8; ++w2) s += red[w2][h][idx];
    float* orow = out + (size_t)(r0 + row) * 26;
    if (h == 0)                 orow[col]      = s + bf0[col];
    else if (h == 1) { if (col < 5) orow[16 + col] = s + bf1[col]; }
    else             { if (col < 5) orow[21 + col] = s + bf2[col]; }
  }
}

// ---------------------------------------------------------------------------
extern "C" void kernel_launch(void* const* d_in, const int* in_sizes, int n_in,
                              void* d_out, int out_size, void* d_ws, size_t ws_size,
                              hipStream_t stream) {
  const float* feat = (const float*)d_in[0];
  const float* W1 = (const float*)d_in[1];
  const float* g1 = (const float*)d_in[2];
  const float* b1 = (const float*)d_in[3];
  const float* m1 = (const float*)d_in[4];
  const float* v1 = (const float*)d_in[5];
  const float* W2 = (const float*)d_in[6];
  const float* g2 = (const float*)d_in[7];
  const float* b2 = (const float*)d_in[8];
  const float* m2 = (const float*)d_in[9];
  const float* v2 = (const float*)d_in[10];
  const float* W3 = (const float*)d_in[11];
  const float* g3 = (const float*)d_in[12];
  const float* b3 = (const float*)d_in[13];
  const float* m3 = (const float*)d_in[14];
  const float* v3 = (const float*)d_in[15];
  const float* Wf0 = (const float*)d_in[16];
  const float* bf0 = (const float*)d_in[17];
  const float* Wf1 = (const float*)d_in[18];
  const float* bf1 = (const float*)d_in[19];
  const float* Wf2 = (const float*)d_in[20];
  const float* bf2 = (const float*)d_in[21];
  float* out = (float*)d_out;

  // workspace: wbuf 24MB | actA 48MB | actB 48MB (features bf16 overlaps actB)
  // Wfb (192KB) reuses wbuf after gemm3 has consumed W3.
  char* ws = (char*)d_ws;
  __hip_bfloat16* wbuf = (__hip_bfloat16*)ws;
  __hip_bfloat16* actA = (__hip_bfloat16*)(ws + 25165824);
  __hip_bfloat16* actB = (__hip_bfloat16*)(ws + 25165824 + 50331648);
  __hip_bfloat16* xb   = actB;
  __hip_bfloat16* Wfb  = wbuf;

  const int nW4 = (3 * CDIM * CDIM) / 4;
  const int nX4 = (MROWS * CDIM) / 4;
  const long long hstride = (long long)MROWS * CDIM;

  cvt_f32_bf16<<<2048, 256, 0, stream>>>(feat, (unsigned short*)xb, nX4);

  cvt_f32_bf16<<<2048, 256, 0, stream>>>(W1, (unsigned short*)wbuf, nW4);
  gemm128_ring<<<768, 512, 0, stream>>>(xb, 0LL, wbuf, g1, b1, m1, v1, actA);

  cvt_f32_bf16<<<2048, 256, 0, stream>>>(W2, (unsigned short*)wbuf, nW4);
  gemm128_ring<<<768, 512, 0, stream>>>(actA, hstride, wbuf, g2, b2, m2, v2, actB);

  cvt_f32_bf16<<<2048, 256, 0, stream>>>(W3, (unsigned short*)wbuf, nW4);
  gemm128_ring<<<768, 512, 0, stream>>>(actB, hstride, wbuf, g3, b3, m3, v3, actA);

  pack_wf<<<384, 256, 0, stream>>>(Wf0, Wf1, Wf2, Wfb);
  final_mfma<<<256, 512, 0, stream>>>(actA, Wfb, bf0, bf1, bf2, out);
}

// Round 7
// 357.469 us; speedup vs baseline: 1.0905x; 1.0167x over previous
//
#include <hip/hip_runtime.h>
#include <hip/hip_bf16.h>

typedef __attribute__((ext_vector_type(8))) short short8;
typedef __attribute__((ext_vector_type(4))) float f32x4;

#define BN_EPS 1e-5f
#define MROWS 4096
#define CDIM 2048
#define NKT 32   // K tiles of 64

#define SB() __builtin_amdgcn_sched_barrier(0)

__device__ __forceinline__ void gload_lds16(const void* g, void* l) {
  __builtin_amdgcn_global_load_lds(
      (const __attribute__((address_space(1))) void*)g,
      (__attribute__((address_space(3))) void*)l, 16, 0, 0);
}

// ---------------------------------------------------------------------------
// fp32 -> bf16 conversion (vectorized float4 -> ushort4)
// ---------------------------------------------------------------------------
__global__ __launch_bounds__(256) void cvt_f32_bf16(const float* __restrict__ in,
                                                    unsigned short* __restrict__ out,
                                                    int n4) {
  int idx = blockIdx.x * blockDim.x + threadIdx.x;
  int stride = gridDim.x * blockDim.x;
  for (int i = idx; i < n4; i += stride) {
    float4 vv = ((const float4*)in)[i];
    __hip_bfloat16 h0 = __float2bfloat16(vv.x);
    __hip_bfloat16 h1 = __float2bfloat16(vv.y);
    __hip_bfloat16 h2 = __float2bfloat16(vv.z);
    __hip_bfloat16 h3 = __float2bfloat16(vv.w);
    ushort4 o;
    o.x = *(unsigned short*)&h0;
    o.y = *(unsigned short*)&h1;
    o.z = *(unsigned short*)&h2;
    o.w = *(unsigned short*)&h3;
    ((ushort4*)out)[i] = o;
  }
}

// ---------------------------------------------------------------------------
// 128x256 tile, BK=64, 3-deep LDS ring (144 KiB, 1 block/CU), grid 768 = 3
// exact rounds. 8 waves (2M x 4N) of 64x64, acc[4][4].
// R7 change: tile t+1's ks0 fragment reads issue UNDER tile t's last MFMA
// group (ring guarantees t+1's staging landed: vmcnt(4) at the mid-tile
// sync point counts only this tile's 4 newer stage-loads). One barrier +
// one {vmcnt lgkmcnt(0)} per K-tile; no serial post-barrier read burst.
// Hazard ledger: writes to slot s happen >=1 barrier after last read of s;
// lgkmcnt(0) at the barrier keeps B1p's post-barrier consumption safe.
// Swizzle chunk^=(row&7) on 16B chunks (R3-verified, 0 conflicts).
// ---------------------------------------------------------------------------
__global__ __launch_bounds__(512, 2) void gemm128_ring(
    const __hip_bfloat16* __restrict__ A, long long a_hstride,
    const __hip_bfloat16* __restrict__ W,
    const float* __restrict__ gp, const float* __restrict__ bp,
    const float* __restrict__ mp, const float* __restrict__ vp,
    __hip_bfloat16* __restrict__ out)
{
  __shared__ __hip_bfloat16 sm[73728];   // 144 KiB = 3 x 24576 elems

  const int tid  = threadIdx.x;
  const int w    = tid >> 6;
  const int lane = tid & 63;

  // XCD-bijective swizzle over 768 blocks (768 % 8 == 0, q = 96)
  const int bid = blockIdx.x;
  const int swz = (bid & 7) * 96 + (bid >> 3);
  const int h   = swz >> 8;          // 256 tiles per head
  const int rem = swz & 255;
  const int mt  = rem >> 3;          // 32 m-tiles of 128
  const int nt  = rem & 7;           // 8 n-tiles of 256

  const __hip_bfloat16* Abase = A + (size_t)h * (size_t)a_hstride + (size_t)(mt * 128) * CDIM;
  const __hip_bfloat16* Bbase = W + ((size_t)h * CDIM + (size_t)(nt * 256)) * CDIM;

  // staging: A tile 128x64 = 1024 16B slots (thread t: slots t, t+512);
  // B tile 256x64 = 2048 slots. slot s: row=s>>3, chunk=s&7,
  // global chunk = chunk ^ (row&7).
  const int row0 = tid >> 3;
  const int ch0  = (tid & 7) ^ (row0 & 7);
  const __hip_bfloat16* aSrc = Abase + (size_t)row0 * CDIM + ch0 * 8;
  const __hip_bfloat16* bSrc = Bbase + (size_t)row0 * CDIM + ch0 * 8;

  // fragment read offsets (swizzled)
  const int wm = w >> 2, wn = w & 3;
  const int fr = lane & 15, fg = lane >> 4;
  const int offs0 = fr * 64 + ((fg ^ (fr & 7)) << 3);        // ksub 0
  const int offs1 = fr * 64 + (((fg + 4) ^ (fr & 7)) << 3);  // ksub 1
  const int aoffs0 = wm * 4096 + offs0;
  const int aoffs1 = wm * 4096 + offs1;
  const int boffs0 = 8192 + wn * 4096 + offs0;
  const int boffs1 = 8192 + wn * 4096 + offs1;

  auto SA = [&](int buf, int t) {
    __hip_bfloat16* dp = &sm[buf + tid * 8];
    gload_lds16(aSrc + t * 64, dp);
    gload_lds16(aSrc + (size_t)64 * CDIM + t * 64, dp + 4096);
  };
  auto SB0 = [&](int buf, int t) {
    __hip_bfloat16* dp = &sm[buf + 8192 + tid * 8];
    gload_lds16(bSrc + t * 64, dp);
    gload_lds16(bSrc + (size_t)64 * CDIM + t * 64, dp + 4096);
  };
  auto SB1 = [&](int buf, int t) {
    __hip_bfloat16* dp = &sm[buf + 8192 + 8192 + tid * 8];
    gload_lds16(bSrc + (size_t)128 * CDIM + t * 64, dp);
    gload_lds16(bSrc + (size_t)192 * CDIM + t * 64, dp + 4096);
  };

  f32x4 acc[4][4] = {};
  short8 Af[4], Ap[4], B0[2], B1[2], B0p[2], B1p[2];

#define LDA4(dst, base)                                                  \
  _Pragma("unroll") for (int i_ = 0; i_ < 4; ++i_)                       \
    dst[i_] = *(const short8*)&sm[(base) + i_ * 1024];
#define LDB2(dst, base, j0)                                              \
  _Pragma("unroll") for (int j_ = 0; j_ < 2; ++j_)                       \
    dst[j_] = *(const short8*)&sm[(base) + ((j0) + j_) * 1024];

#define MFMA_G(joff, Aset, Bset)                                         \
  __builtin_amdgcn_s_setprio(1);                                         \
  _Pragma("unroll") for (int i_ = 0; i_ < 4; ++i_)                       \
  _Pragma("unroll") for (int j_ = 0; j_ < 2; ++j_)                       \
    acc[i_][j_ + joff] = __builtin_amdgcn_mfma_f32_16x16x32_bf16(        \
        Aset[i_], Bset[j_], acc[i_][j_ + joff], 0, 0, 0);                \
  __builtin_amdgcn_s_setprio(0);

  // ---- prologue: stage tiles 0,1 into ring slots 0,1; read t0 ks0 frags ----
  SA(0, 0); SB0(0, 0); SB1(0, 0);
  SA(24576, 1); SB0(24576, 1); SB1(24576, 1);
  asm volatile("s_waitcnt vmcnt(6)" ::: "memory");
  SB();
  __builtin_amdgcn_s_barrier();
  SB();
  LDA4(Af, 0 + aoffs0);
  LDB2(B0, 0 + boffs0, 0);
  LDB2(B1, 0 + boffs0, 2);
  SB();

  int oc = 0, on = 24576, os = 49152;
  for (int t = 0; t < NKT; ++t) {
    // g0: ks0 j01; refill B0p <- ks1(oc)
    MFMA_G(0, Af, B0); SB();
    LDB2(B0p, oc + boffs1, 0); SB();
    // g1: ks0 j23; refill Ap <- ks1(oc); stage A(t+2) -> os
    MFMA_G(2, Af, B1); SB();
    LDA4(Ap, oc + aoffs1);
    if (t + 2 < NKT) SA(os, t + 2);
    SB();
    // g2: ks1 j01; refill B1p <- ks1(oc); stage B0(t+2) -> os
    MFMA_G(0, Ap, B0p); SB();
    LDB2(B1p, oc + boffs1, 2);
    if (t + 2 < NKT) SB0(os, t + 2);
    SB();
    // mid-tile sync: t+1's staging landed (4 newer stage-loads outstanding);
    // lgkmcnt(0) so B1p (consumed after barrier) completes before any rewrite.
    if (t + 1 < NKT) {
      if (t + 2 < NKT) { asm volatile("s_waitcnt vmcnt(4) lgkmcnt(0)" ::: "memory"); }
      else             { asm volatile("s_waitcnt vmcnt(0) lgkmcnt(0)" ::: "memory"); }
      SB();
      __builtin_amdgcn_s_barrier();
      SB();
    }
    // g3: ks1 j23; stage B1(t+2) -> os; read t+1 ks0 frags (on) under MFMA
    MFMA_G(2, Ap, B1p); SB();
    if (t + 2 < NKT) SB1(os, t + 2);
    if (t + 1 < NKT) {
      LDA4(Af, on + aoffs0);
      LDB2(B0, on + boffs0, 0);
      LDB2(B1, on + boffs0, 2);
    }
    SB();
    const int tmp = oc; oc = on; on = os; os = tmp;
  }

  // epilogue: BN (folded) + ReLU, bf16 store.
  // C/D layout: col = lane&15, row = (lane>>4)*4 + reg  [m89 verified]
  const float* gh = gp + h * CDIM;
  const float* bh = bp + h * CDIM;
  const float* mh = mp + h * CDIM;
  const float* vh = vp + h * CDIM;
  const int colBase = nt * 256 + wn * 64 + fr;
  const int rowBase = mt * 128 + wm * 64 + fg * 4;
#pragma unroll
  for (int j = 0; j < 4; ++j) {
    const int col = colBase + j * 16;
    const float sc = gh[col] / sqrtf(vh[col] + BN_EPS);
    const float sh = bh[col] - mh[col] * sc;
#pragma unroll
    for (int i = 0; i < 4; ++i) {
      const int row = rowBase + i * 16;
#pragma unroll
      for (int rr = 0; rr < 4; ++rr) {
        float val = acc[i][j][rr] * sc + sh;
        val = val > 0.f ? val : 0.f;
        out[((size_t)h * MROWS + row + rr) * CDIM + col] = __float2bfloat16(val);
      }
    }
  }
}

// ---------------------------------------------------------------------------
// Pack final-layer weights into bf16 Wfb[3][16][2048], zero-padded.
// ---------------------------------------------------------------------------
__global__ __launch_bounds__(256) void pack_wf(
    const float* __restrict__ Wf0, const float* __restrict__ Wf1,
    const float* __restrict__ Wf2, __hip_bfloat16* __restrict__ Wfb) {
  int idx = blockIdx.x * 256 + threadIdx.x;   // 3*16*2048 = 98304
  if (idx >= 3 * 16 * CDIM) return;
  int h = idx / (16 * CDIM);
  int rem = idx - h * 16 * CDIM;
  int j = rem / CDIM;
  int k = rem - j * CDIM;
  float v = 0.f;
  if (h == 0)            v = Wf0[j * CDIM + k];
  else if (h == 1)       { if (j < 5) v = Wf1[j * CDIM + k]; }
  else                   { if (j < 5) v = Wf2[j * CDIM + k]; }
  Wfb[idx] = __float2bfloat16(v);
}

// ---------------------------------------------------------------------------
// Final 1x1 convs via MFMA, K-split 8 ways across waves.
// ---------------------------------------------------------------------------
__global__ __launch_bounds__(512) void final_mfma(
    const __hip_bfloat16* __restrict__ act,   // [3][4096][2048]
    const __hip_bfloat16* __restrict__ Wfb,   // [3][16][2048]
    const float* __restrict__ bf0, const float* __restrict__ bf1,
    const float* __restrict__ bf2, float* __restrict__ out)  // [4096][26]
{
  __shared__ float red[8][3][256];
  const int tid  = threadIdx.x;
  const int w    = tid >> 6;
  const int lane = tid & 63;
  const int r0   = blockIdx.x * 16;
  const int fr   = lane & 15;
  const int fk   = (lane >> 4) * 8;
  const int kbase = w * 256 + fk;

  f32x4 acc[3] = {};
  const __hip_bfloat16* aRow = act + (size_t)(r0 + fr) * CDIM + kbase;
  const __hip_bfloat16* bRow = Wfb + (size_t)fr * CDIM + kbase;
#pragma unroll
  for (int ks = 0; ks < 8; ++ks) {
    const int k = ks * 32;
#pragma unroll
    for (int h = 0; h < 3; ++h) {
      short8 a = *(const short8*)(aRow + (size_t)h * MROWS * CDIM + k);
      short8 b = *(const short8*)(bRow + h * 16 * CDIM + k);
      acc[h] = __builtin_amdgcn_mfma_f32_16x16x32_bf16(a, b, acc[h], 0, 0, 0);
    }
  }

  const int rb = (lane >> 4) * 4;
#pragma unroll
  for (int h = 0; h < 3; ++h)
#pragma unroll
    for (int r = 0; r < 4; ++r)
      red[w][h][(rb + r) * 16 + fr] = acc[h][r];
  __syncthreads();

  for (int e = tid; e < 768; e += 512) {
    const int h = e >> 8, idx = e & 255;
    const int row = idx >> 4, col = idx & 15;
    float s = 0.f;
#pragma unroll
    for (int w2 = 0; w2 < 8; ++w2) s += red[w2][h][idx];
    float* orow = out + (size_t)(r0 + row) * 26;
    if (h == 0)                 orow[col]      = s + bf0[col];
    else if (h == 1) { if (col < 5) orow[16 + col] = s + bf1[col]; }
    else             { if (col < 5) orow[21 + col] = s + bf2[col]; }
  }
}

// ---------------------------------------------------------------------------
extern "C" void kernel_launch(void* const* d_in, const int* in_sizes, int n_in,
                              void* d_out, int out_size, void* d_ws, size_t ws_size,
                              hipStream_t stream) {
  const float* feat = (const float*)d_in[0];
  const float* W1 = (const float*)d_in[1];
  const float* g1 = (const float*)d_in[2];
  const float* b1 = (const float*)d_in[3];
  const float* m1 = (const float*)d_in[4];
  const float* v1 = (const float*)d_in[5];
  const float* W2 = (const float*)d_in[6];
  const float* g2 = (const float*)d_in[7];
  const float* b2 = (const float*)d_in[8];
  const float* m2 = (const float*)d_in[9];
  const float* v2 = (const float*)d_in[10];
  const float* W3 = (const float*)d_in[11];
  const float* g3 = (const float*)d_in[12];
  const float* b3 = (const float*)d_in[13];
  const float* m3 = (const float*)d_in[14];
  const float* v3 = (const float*)d_in[15];
  const float* Wf0 = (const float*)d_in[16];
  const float* bf0 = (const float*)d_in[17];
  const float* Wf1 = (const float*)d_in[18];
  const float* bf1 = (const float*)d_in[19];
  const float* Wf2 = (const float*)d_in[20];
  const float* bf2 = (const float*)d_in[21];
  float* out = (float*)d_out;

  // workspace: wbuf 24MB | actA 48MB | actB 48MB (features bf16 overlaps actB)
  // Wfb (192KB) reuses wbuf after gemm3 has consumed W3.
  char* ws = (char*)d_ws;
  __hip_bfloat16* wbuf = (__hip_bfloat16*)ws;
  __hip_bfloat16* actA = (__hip_bfloat16*)(ws + 25165824);
  __hip_bfloat16* actB = (__hip_bfloat16*)(ws + 25165824 + 50331648);
  __hip_bfloat16* xb   = actB;
  __hip_bfloat16* Wfb  = wbuf;

  const int nW4 = (3 * CDIM * CDIM) / 4;
  const int nX4 = (MROWS * CDIM) / 4;
  const long long hstride = (long long)MROWS * CDIM;

  cvt_f32_bf16<<<2048, 256, 0, stream>>>(feat, (unsigned short*)xb, nX4);

  cvt_f32_bf16<<<2048, 256, 0, stream>>>(W1, (unsigned short*)wbuf, nW4);
  gemm128_ring<<<768, 512, 0, stream>>>(xb, 0LL, wbuf, g1, b1, m1, v1, actA);

  cvt_f32_bf16<<<2048, 256, 0, stream>>>(W2, (unsigned short*)wbuf, nW4);
  gemm128_ring<<<768, 512, 0, stream>>>(actA, hstride, wbuf, g2, b2, m2, v2, actB);

  cvt_f32_bf16<<<2048, 256, 0, stream>>>(W3, (unsigned short*)wbuf, nW4);
  gemm128_ring<<<768, 512, 0, stream>>>(actB, hstride, wbuf, g3, b3, m3, v3, actA);

  pack_wf<<<384, 256, 0, stream>>>(Wf0, Wf1, Wf2, Wfb);
  final_mfma<<<256, 512, 0, stream>>>(actA, Wfb, bf0, bf1, bf2, out);
}